// Round 1
// baseline (100.768 us; speedup 1.0000x reference)
//
#include <hip/hip_runtime.h>
#include <math.h>

// Biquad peaking EQ over [B=8, C=2, T=1200000] f32.
// Strategy: stable IIR => finite effective memory. Chunk time axis; each
// thread processes W warm-up samples (from zero state) + L output samples
// serially. Truncation error ~ r^W * |state|, r=0.9313 => ~5e-4 for W=160.

#define T_LEN   1200000
#define NCH     16            // 8*2 independent channels
#define L_CHUNK 160           // output samples per thread (divides T_LEN: 7500 chunks)
#define W_WARM  160           // warm-up samples (multiple of 4)
#define NC_PER  (T_LEN / L_CHUNK)     // 7500
#define NTHREADS (NCH * NC_PER)       // 120000

__global__ __launch_bounds__(256) void eq_biquad_kernel(
    const float* __restrict__ x, float* __restrict__ y,
    float b0, float b1, float b2, float a1, float a2)
{
    int tid = blockIdx.x * blockDim.x + threadIdx.x;
    if (tid >= NTHREADS) return;
    int ch = tid / NC_PER;
    int c  = tid - ch * NC_PER;

    const float* xc = x + (size_t)ch * T_LEN;
    float*       yc = y + (size_t)ch * T_LEN;

    int start = c * L_CHUNK;
    int n0 = start - W_WARM;
    if (n0 < 0) n0 = 0;          // first chunk: exact zero initial conditions

    float x1 = 0.f, x2 = 0.f, y1 = 0.f, y2 = 0.f;
    if (n0 > 0) {                 // n0 >= L_CHUNK here, so n0-2 >= 0
        x1 = xc[n0 - 1];
        x2 = xc[n0 - 2];
    }

    const float4* xv = (const float4*)xc;   // base is 16B aligned (T_LEN*4 % 16 == 0)
    float4*       yv = (float4*)yc;

    // one biquad step; critical path is the single fma through y1
#define STEP(xi, yo)                                              \
    {                                                             \
        float f = fmaf(b0, (xi), fmaf(b1, x1, b2 * x2));          \
        float t = fmaf(-a2, y2, f);                               \
        (yo) = fmaf(-a1, y1, t);                                  \
        y2 = y1; y1 = (yo);                                       \
        x2 = x1; x1 = (xi);                                       \
    }

    // warm-up: run the recurrence, discard outputs
    for (int n = n0; n < start; n += 4) {
        float4 v = xv[n >> 2];
        float d;
        STEP(v.x, d); STEP(v.y, d); STEP(v.z, d); STEP(v.w, d);
        (void)d;
    }

    // main: compute and store L_CHUNK samples
    for (int n = start; n < start + L_CHUNK; n += 4) {
        float4 v = xv[n >> 2];
        float4 o;
        STEP(v.x, o.x); STEP(v.y, o.y); STEP(v.z, o.z); STEP(v.w, o.w);
        yv[n >> 2] = o;
    }
#undef STEP
}

extern "C" void kernel_launch(void* const* d_in, const int* in_sizes, int n_in,
                              void* d_out, int out_size, void* d_ws, size_t ws_size,
                              hipStream_t stream) {
    const float* x = (const float*)d_in[0];
    float* y = (float*)d_out;

    // torchaudio peaking-EQ coefficients (computed in double, cast to f32,
    // matching the reference's np.float32(b/a0))
    double w0    = 2.0 * M_PI * 1000.0 / 44100.0;
    double A     = exp(6.0 / 40.0 * log(10.0));
    double alpha = sin(w0) / (2.0 * 0.707);
    double b0 = 1.0 + alpha * A;
    double b1 = -2.0 * cos(w0);
    double b2 = 1.0 - alpha * A;
    double a0 = 1.0 + alpha / A;
    double a1 = -2.0 * cos(w0);
    double a2 = 1.0 - alpha / A;

    float fb0 = (float)(b0 / a0), fb1 = (float)(b1 / a0), fb2 = (float)(b2 / a0);
    float fa1 = (float)(a1 / a0), fa2 = (float)(a2 / a0);

    int blocks = (NTHREADS + 255) / 256;
    eq_biquad_kernel<<<blocks, 256, 0, stream>>>(x, y, fb0, fb1, fb2, fa1, fa2);
}

// Round 2
// 53.434 us; speedup vs baseline: 1.8858x; 1.8858x over previous
//
#include <hip/hip_runtime.h>
#include <math.h>

// Biquad peaking EQ over [B=8, C=2, T=1200000] f32.
// Round 2: LDS-staged, coalesced global access.
//  - Each 128-thread block stages 128 rows x 64 samples (32 KB) of one
//    channel, time-contiguous, via coalesced float4 loads.
//  - Rows 0..1 are warm-up-only (overlap with previous segment); thread i
//    (i>=2) runs W=128 warm-up steps from rows i-2,i-1 (already in LDS!)
//    then computes row i, writing y back into its own row.
//  - XOR swizzle word = row*64 + (t ^ (row&31)) makes every LDS access
//    pattern 2 lanes/bank (free) with no padding.
//  - Coalesced float4 store-out of rows 2..127.
// Truncation: r=0.9313 per sample; r^128 * |state| * (1/sin w0) ~ 4e-3.

#define T_LEN   1200000
#define NCH     16
#define BT      128                     // threads per block
#define ROWS    128                     // LDS rows of 64 samples
#define OUT_ROWS (ROWS - 2)             // 126 output rows per block
#define OUT_PER_BLOCK (OUT_ROWS * 64)   // 8064
#define SEGS ((T_LEN + OUT_PER_BLOCK - 1) / OUT_PER_BLOCK)  // 149

__global__ __launch_bounds__(BT) void eq_biquad_kernel(
    const float* __restrict__ x, float* __restrict__ y,
    float b0, float b1, float b2, float a1, float a2)
{
    __shared__ float lds[ROWS * 64];    // 32 KB

    const int tid = threadIdx.x;
    const int seg = blockIdx.x;
    const int ch  = blockIdx.y;
    const float* __restrict__ xc = x + (size_t)ch * T_LEN;
    float*       __restrict__ yc = y + (size_t)ch * T_LEN;

    // global sample index of LDS local sample 0 (may be negative for seg 0)
    const long g0 = (long)seg * OUT_PER_BLOCK - 128;

    // ---- stage: coalesced float4 loads, swizzled LDS scatter ----
    // g0 % 4 == 0 and T_LEN % 4 == 0, so each float4 is entirely in or out.
    for (int v = tid; v < ROWS * 16; v += BT) {
        int q = v << 2;                 // local sample index
        long g = g0 + q;
        float4 val = {0.f, 0.f, 0.f, 0.f};
        if (g >= 0 && g < T_LEN) val = *(const float4*)(xc + g);
        int row = q >> 6, t0 = q & 63, m = row & 31, base = row << 6;
        lds[base + ((t0 + 0) ^ m)] = val.x;
        lds[base + ((t0 + 1) ^ m)] = val.y;
        lds[base + ((t0 + 2) ^ m)] = val.z;
        lds[base + ((t0 + 3) ^ m)] = val.w;
    }
    __syncthreads();

    float x1 = 0.f, x2 = 0.f, y1 = 0.f, y2 = 0.f;

#define STEP(xi, yo)                                              \
    {                                                             \
        float f = fmaf(b0, (xi), fmaf(b1, x1, b2 * x2));          \
        float t_ = fmaf(-a2, y2, f);                              \
        (yo) = fmaf(-a1, y1, t_);                                 \
        y2 = y1; y1 = (yo);                                       \
        x2 = x1; x1 = (xi);                                       \
    }

    // ---- warm-up: local samples [max(0,(tid-2)*64), tid*64), from LDS ----
    {
        int qs = (tid - 2) << 6; if (qs < 0) qs = 0;
        const int qm = tid << 6;        // trip count = 128 for tid >= 2
        #pragma unroll 4
        for (int q = qs; q < qm; ++q) {
            int row = q >> 6;
            float xv = lds[(row << 6) + ((q & 63) ^ (row & 31))];
            float d; STEP(xv, d); (void)d;
        }
    }
    __syncthreads();   // all warm-up reads done before any main-phase write

    // ---- main: compute row tid, write y back into the same LDS row ----
    {
        const int base = tid << 6, m = tid & 31;
        #pragma unroll 4
        for (int t = 0; t < 64; ++t) {
            int w = base + (t ^ m);
            float xv = lds[w];
            float yv; STEP(xv, yv);
            lds[w] = yv;
        }
    }
    __syncthreads();
#undef STEP

    // ---- store out rows 2..127: coalesced float4 ----
    for (int v = tid; v < OUT_ROWS * 16; v += BT) {
        int q = 128 + (v << 2);
        long g = g0 + q;                // = seg*8064 + v*4  (>= 0)
        if (g < T_LEN) {
            int row = q >> 6, t0 = q & 63, m = row & 31, base = row << 6;
            float4 val;
            val.x = lds[base + ((t0 + 0) ^ m)];
            val.y = lds[base + ((t0 + 1) ^ m)];
            val.z = lds[base + ((t0 + 2) ^ m)];
            val.w = lds[base + ((t0 + 3) ^ m)];
            *(float4*)(yc + g) = val;
        }
    }
}

extern "C" void kernel_launch(void* const* d_in, const int* in_sizes, int n_in,
                              void* d_out, int out_size, void* d_ws, size_t ws_size,
                              hipStream_t stream) {
    const float* x = (const float*)d_in[0];
    float* y = (float*)d_out;

    // torchaudio peaking-EQ coefficients (double, then cast, matching ref)
    double w0    = 2.0 * M_PI * 1000.0 / 44100.0;
    double A     = exp(6.0 / 40.0 * log(10.0));
    double alpha = sin(w0) / (2.0 * 0.707);
    double b0 = 1.0 + alpha * A;
    double b1 = -2.0 * cos(w0);
    double b2 = 1.0 - alpha * A;
    double a0 = 1.0 + alpha / A;
    double a1 = -2.0 * cos(w0);
    double a2 = 1.0 - alpha / A;

    float fb0 = (float)(b0 / a0), fb1 = (float)(b1 / a0), fb2 = (float)(b2 / a0);
    float fa1 = (float)(a1 / a0), fa2 = (float)(a2 / a0);

    dim3 grid(SEGS, NCH);
    eq_biquad_kernel<<<grid, BT, 0, stream>>>(x, y, fb0, fb1, fb2, fa1, fa2);
}

// Round 3
// 35.318 us; speedup vs baseline: 2.8532x; 1.5130x over previous
//
#include <hip/hip_runtime.h>
#include <math.h>

// Biquad peaking EQ over [B=8, C=2, T=1200000] f32.
// Round 3: affine-scan parallelization of the IIR.
//   y[n] = f[n] - a1*y[n-1] - a2*y[n-2],  f = FIR(x)
//   state s=(y[n],y[n-1]):  s' = M*s + (f,0),  M = [[-a1,-a2],[1,0]]
// Per 64-lane block: each lane owns a row of L=32 samples.
//   Phase A: zero-state recurrence over own row (32-step serial chain),
//            y_zs written back to LDS in place over x; exit state v kept.
//   Scan:    inclusive affine scan over lanes via 6 shfl_up steps with
//            constant matrices M^(32*2^k) (host-precomputed in double).
//   Store:   y[t] = y_zs[t] + alpha*c1[t] + beta*c2[t] fused into the
//            coalesced float4 store (c1,c2 = homogeneous solutions from
//            closed form phi[t] = r^t sin((t+1)theta)/sin(theta)).
// Rows 0..3 are warm-up (128 samples): truncation r^128*|state| ~ 1e-2,
// matches round-2's measured absmax 0.0156 << 0.119 threshold.
// LDS fully swizzled (word = row*32 + (j ^ (row&31))): every access
// pattern is 2 lanes/bank (free on CDNA4).

#define T_LEN 1200000
#define NCH   16
#define L     32                        // samples per row (= per lane)
#define NR    64                        // rows per block = lanes
#define NWARM 4                         // warm-up rows (128 samples)
#define OUT_ROWS (NR - NWARM)           // 60
#define OUT_PER_BLOCK (OUT_ROWS * L)    // 1920
#define SEGS (T_LEN / OUT_PER_BLOCK)    // 625 (exact)
#define STAGE_FLOATS (NR * L)           // 2048

struct Params {
    float b0, b1, b2, a1, a2;
    float lnr, theta, inv_sinth;
    float C[6][4];                      // [k] = M^(L*2^k) row-major {m00,m01,m10,m11}
};

__global__ __launch_bounds__(64) void eq_kernel(const float* __restrict__ x,
                                                float* __restrict__ y, Params P)
{
    __shared__ __align__(16) float xs[STAGE_FLOATS];   // x, then y_zs in place
    __shared__ float alpha[NR], beta[NR];
    __shared__ __align__(16) float c1t[L];
    __shared__ __align__(16) float c2t[L];

    const int lane = threadIdx.x;
    const int seg  = blockIdx.x;
    const int ch   = blockIdx.y;
    const float* __restrict__ xc = x + (size_t)ch * T_LEN;
    float*       __restrict__ yc = y + (size_t)ch * T_LEN;
    const int g0 = seg * OUT_PER_BLOCK - NWARM * L;    // may be -128 for seg 0

    // ---- one-time per block: c-table via closed form ----
    if (lane < L) {
        int t = lane;
        float pht   = expf(t * P.lnr) * sinf((t + 1) * P.theta) * P.inv_sinth;
        float phtm1 = (t == 0) ? 0.f
                               : expf((t - 1) * P.lnr) * sinf(t * P.theta) * P.inv_sinth;
        c1t[t] = -P.a1 * pht - P.a2 * phtm1;   // response to y[-1]=1
        c2t[t] = -P.a2 * pht;                  // response to y[-2]=1
    }

    // ---- stage x -> LDS: coalesced float4 loads, swizzled scatter ----
    #pragma unroll
    for (int it = 0; it < STAGE_FLOATS / 4 / 64; ++it) {   // 8 iters
        int v = it * 64 + lane;
        int q = v << 2;
        int g = g0 + q;                                    // multiple of 4
        float4 val = make_float4(0.f, 0.f, 0.f, 0.f);
        if (g >= 0 && g < T_LEN) val = *(const float4*)(xc + g);
        int row = q >> 5, j = q & 31, m = row & 31, base = row << 5;
        xs[base + ((j + 0) ^ m)] = val.x;
        xs[base + ((j + 1) ^ m)] = val.y;
        xs[base + ((j + 2) ^ m)] = val.z;
        xs[base + ((j + 3) ^ m)] = val.w;
    }
    __syncthreads();

    // ---- Phase A: zero-state run over own row, y_zs written in place ----
    float v1 = 0.f, v2 = 0.f;                 // state (y[n], y[n-1]), zero init
    {
        const int row = lane, m = row & 31, base = row << 5;
        float x1, x2;
        if (row > 0) {                        // prev row's tail (read BEFORE any
            int pb = (row - 1) << 5;          //  lane overwrites it; same-wave
            int pm = (row - 1) & 31;          //  lockstep => read precedes writes)
            x1 = xs[pb + (31 ^ pm)];
            x2 = xs[pb + (30 ^ pm)];
        } else { x1 = 0.f; x2 = 0.f; }        // block prehistory ~ warm-up trunc.
        #pragma unroll 8
        for (int j = 0; j < L; ++j) {
            int w = base + (j ^ m);
            float xv = xs[w];
            float f  = fmaf(P.b0, xv, fmaf(P.b1, x1, P.b2 * x2));
            float t2 = fmaf(-P.a2, v2, f);
            float yv = fmaf(-P.a1, v1, t2);
            v2 = v1; v1 = yv;
            x2 = x1; x1 = xv;
            xs[w] = yv;                        // y_zs over x, same slot
        }
    }

    // ---- inclusive affine scan across 64 lanes: s_t = C*s_{t-1} + v ----
    #pragma unroll
    for (int k = 0; k < 6; ++k) {
        int d = 1 << k;
        float p1 = __shfl_up(v1, d);
        float p2 = __shfl_up(v2, d);
        if (lane < d) { p1 = 0.f; p2 = 0.f; }
        float n1 = fmaf(P.C[k][0], p1, fmaf(P.C[k][1], p2, v1));
        float n2 = fmaf(P.C[k][2], p1, fmaf(P.C[k][3], p2, v2));
        v1 = n1; v2 = n2;
    }
    // entry state of row t = exit state of row t-1
    {
        float a_ = __shfl_up(v1, 1);
        float b_ = __shfl_up(v2, 1);
        if (lane == 0) { a_ = 0.f; b_ = 0.f; }
        alpha[lane] = a_; beta[lane] = b_;
    }
    __syncthreads();

    // ---- store with fused correction: coalesced float4 out ----
    for (int vo = lane; vo < OUT_PER_BLOCK / 4; vo += 64) {   // 480/64 = 7.5
        int q = (vo << 2) + NWARM * L;
        int row = q >> 5, j = q & 31, m = row & 31, base = row << 5;
        float al = alpha[row], be = beta[row];
        float4 c1v = *(const float4*)&c1t[j];
        float4 c2v = *(const float4*)&c2t[j];
        float4 o4;
        o4.x = fmaf(al, c1v.x, fmaf(be, c2v.x, xs[base + ((j + 0) ^ m)]));
        o4.y = fmaf(al, c1v.y, fmaf(be, c2v.y, xs[base + ((j + 1) ^ m)]));
        o4.z = fmaf(al, c1v.z, fmaf(be, c2v.z, xs[base + ((j + 2) ^ m)]));
        o4.w = fmaf(al, c1v.w, fmaf(be, c2v.w, xs[base + ((j + 3) ^ m)]));
        *(float4*)(yc + g0 + q) = o4;          // g0+q in [seg*1920, seg*1920+1920)
    }
}

extern "C" void kernel_launch(void* const* d_in, const int* in_sizes, int n_in,
                              void* d_out, int out_size, void* d_ws, size_t ws_size,
                              hipStream_t stream) {
    const float* x = (const float*)d_in[0];
    float* y = (float*)d_out;

    // torchaudio peaking-EQ coefficients (double, then cast — matches ref)
    double w0    = 2.0 * M_PI * 1000.0 / 44100.0;
    double A     = exp(6.0 / 40.0 * log(10.0));
    double al    = sin(w0) / (2.0 * 0.707);
    double b0 = 1.0 + al * A;
    double b1 = -2.0 * cos(w0);
    double b2 = 1.0 - al * A;
    double a0 = 1.0 + al / A;
    double a1 = -2.0 * cos(w0);
    double a2 = 1.0 - al / A;
    b0 /= a0; b1 /= a0; b2 /= a0; a1 /= a0; a2 /= a0;

    Params P;
    P.b0 = (float)b0; P.b1 = (float)b1; P.b2 = (float)b2;
    P.a1 = (float)a1; P.a2 = (float)a2;

    double r     = sqrt(a2);
    double theta = acos(-a1 / (2.0 * r));
    P.lnr = (float)log(r);
    P.theta = (float)theta;
    P.inv_sinth = (float)(1.0 / sin(theta));

    // M^(L*2^k) via repeated squaring in double
    double m00 = -a1, m01 = -a2, m10 = 1.0, m11 = 0.0;
    // square 5 times -> M^32
    for (int s = 0; s < 5; ++s) {
        double t00 = m00 * m00 + m01 * m10;
        double t01 = m00 * m01 + m01 * m11;
        double t10 = m10 * m00 + m11 * m10;
        double t11 = m10 * m01 + m11 * m11;
        m00 = t00; m01 = t01; m10 = t10; m11 = t11;
    }
    for (int k = 0; k < 6; ++k) {
        P.C[k][0] = (float)m00; P.C[k][1] = (float)m01;
        P.C[k][2] = (float)m10; P.C[k][3] = (float)m11;
        double t00 = m00 * m00 + m01 * m10;
        double t01 = m00 * m01 + m01 * m11;
        double t10 = m10 * m00 + m11 * m10;
        double t11 = m10 * m01 + m11 * m11;
        m00 = t00; m01 = t01; m10 = t10; m11 = t11;
    }

    dim3 grid(SEGS, NCH);
    eq_kernel<<<grid, 64, 0, stream>>>(x, y, P);
}